// Round 12
// baseline (132.296 us; speedup 1.0000x reference)
//
#include <hip/hip_runtime.h>
#include <hip/hip_bf16.h>

// Problem constants (from reference)
constexpr int B = 16;
constexpr int N = 8192;
constexpr int H = 768;
constexpr int Q = 32;      // K_SEEDS
constexpr int K = 128;     // TOPK
#define SCALE 0.28867513459481287f   // 12^-0.5

typedef __attribute__((ext_vector_type(8))) short bf16x8_t;
typedef __attribute__((ext_vector_type(4))) float f32x4_t;

// LDS: xs[3 planes][128 n][64 B] only (seed fragments live in L2)
#define XS_PLANE 8192      // 128 rows * 64 B
#define LDS_BYTES 24576

__device__ __forceinline__ float bf16_to_f32(ushort h) {
  return __uint_as_float(((uint32_t)h) << 16);
}
__device__ __forceinline__ ushort cvt_bf16(float f) {
  __hip_bfloat16 h = __float2bfloat16(f);
  return __builtin_bit_cast(unsigned short, h);
}
// manual RNE for the prep kernel (cost irrelevant there)
__device__ __forceinline__ ushort f32_to_bf16_rn(float f) {
  uint32_t u = __float_as_uint(f);
  uint32_t r = (u + 0x7FFFu + ((u >> 16) & 1u)) >> 16;
  return (ushort)r;
}
__device__ __forceinline__ void split3_rn(float f, ushort& h, ushort& m, ushort& l) {
  h = f32_to_bf16_rn(f);
  float f1 = f - bf16_to_f32(h);
  m = f32_to_bf16_rn(f1);
  float f2 = f1 - bf16_to_f32(m);
  l = f32_to_bf16_rn(f2);
}
// hot path: HW cvt split; residuals Sterbenz-exact.
// 3-split/6-pass REQUIRED (round 9: dropping 2^-18 term families costs
// ~0.01 absmax each vs the 0.0108 threshold).
__device__ __forceinline__ void split3(float f, ushort& h, ushort& m, ushort& l) {
  h = cvt_bf16(f);
  float f1 = f - bf16_to_f32(h);
  m = cvt_bf16(f1);
  float f2 = f1 - bf16_to_f32(m);
  l = cvt_bf16(f2);
}

// swizzled frag access: 16 B at (row, 16-B sub-block), XOR'd by row
__device__ __forceinline__ bf16x8_t ld_frag(const char* p, int row, int l4) {
  int sb = l4 ^ ((row >> 1) & 3);
  return *reinterpret_cast<const bf16x8_t*>(p + row * 64 + (sb << 4));
}

#define MFMA(a, b, c) __builtin_amdgcn_mfma_f32_16x16x32_bf16(a, b, c, 0, 0, 0)

// ---------------------------------------------------------------------------
// Prep: split seed into bf16 hi/mid/lo in MFMA A-fragment layout (round-7
// verified). sfrag[((c*3+s)*2+t)*64 + lane] = 8 bf16 of
// seed[q = t*16 + (lane&15)][h = c*32 + (lane>>4)*8 ..+8]. 24 blocks x 64.
// ---------------------------------------------------------------------------
__global__ void k_seedsplit(const float* __restrict__ seed,
                            uint4* __restrict__ sfrag) {
  const int c = blockIdx.x;
  const int lane = threadIdx.x;
  const int l15 = lane & 15;
  const int l4 = lane >> 4;
#pragma unroll
  for (int t = 0; t < 2; ++t) {
    const float* sp = seed + (size_t)(t * 16 + l15) * H + c * 32 + l4 * 8;
    ushort uh[8], um[8], ul[8];
#pragma unroll
    for (int e = 0; e < 8; ++e) split3_rn(sp[e], uh[e], um[e], ul[e]);
    uint4 rh, rm, rl;
    rh.x = uh[0] | ((uint32_t)uh[1] << 16); rh.y = uh[2] | ((uint32_t)uh[3] << 16);
    rh.z = uh[4] | ((uint32_t)uh[5] << 16); rh.w = uh[6] | ((uint32_t)uh[7] << 16);
    rm.x = um[0] | ((uint32_t)um[1] << 16); rm.y = um[2] | ((uint32_t)um[3] << 16);
    rm.z = um[4] | ((uint32_t)um[5] << 16); rm.w = um[6] | ((uint32_t)um[7] << 16);
    rl.x = ul[0] | ((uint32_t)ul[1] << 16); rl.y = ul[2] | ((uint32_t)ul[3] << 16);
    rl.z = ul[4] | ((uint32_t)ul[5] << 16); rl.w = ul[6] | ((uint32_t)ul[7] << 16);
    sfrag[((c * 3 + 0) * 2 + t) * 64 + lane] = rh;
    sfrag[((c * 3 + 1) * 2 + t) * 64 + lane] = rm;
    sfrag[((c * 3 + 2) * 2 + t) * 64 + lane] = rl;
  }
}

// Stage one 32-h x chunk: split px (4 rows x 4 h) -> 3 LDS planes
#define STAGE_CHUNK(PX)                                                        \
  {                                                                            \
    _Pragma("unroll") for (int r = 0; r < 4; ++r) {                            \
      const int row = sn + r * 32;                                             \
      const int byt = sh * 2;                                                  \
      const int sb = (byt >> 4) ^ ((row >> 1) & 3);                            \
      char* dst = lds + row * 64 + (sb << 4) + (byt & 15);                     \
      ushort4 uh, um, ul;                                                      \
      split3(PX[r].x, uh.x, um.x, ul.x);                                       \
      split3(PX[r].y, uh.y, um.y, ul.y);                                       \
      split3(PX[r].z, uh.z, um.z, ul.z);                                       \
      split3(PX[r].w, uh.w, um.w, ul.w);                                       \
      *reinterpret_cast<ushort4*>(dst + 0 * XS_PLANE) = uh;                    \
      *reinterpret_cast<ushort4*>(dst + 1 * XS_PLANE) = um;                    \
      *reinterpret_cast<ushort4*>(dst + 2 * XS_PLANE) = ul;                    \
    }                                                                          \
  }

// Load the 6 seed A-frags for chunk C from L2 (issued pre-barrier; latency
// drains during __syncthreads).
#define LOAD_AFRAGS(C, F)                                                      \
  {                                                                            \
    const uint4* sf = sfrag + (C) * 384 + lane;                                \
    F##0 = sf[0 * 64]; F##1 = sf[1 * 64]; F##2 = sf[2 * 64];                   \
    F##3 = sf[3 * 64]; F##4 = sf[4 * 64]; F##5 = sf[5 * 64];                   \
  }

// One chunk of MFMA: 6 LDS B-frag reads + 24 mfma (6 passes x 4 C-tiles)
#define MFMA_CHUNK(F)                                                          \
  {                                                                            \
    const bf16x8_t a0H = __builtin_bit_cast(bf16x8_t, F##0);                   \
    const bf16x8_t a1H = __builtin_bit_cast(bf16x8_t, F##1);                   \
    const bf16x8_t a0M = __builtin_bit_cast(bf16x8_t, F##2);                   \
    const bf16x8_t a1M = __builtin_bit_cast(bf16x8_t, F##3);                   \
    const bf16x8_t a0L = __builtin_bit_cast(bf16x8_t, F##4);                   \
    const bf16x8_t a1L = __builtin_bit_cast(bf16x8_t, F##5);                   \
    bf16x8_t b0H = ld_frag(lds + 0 * XS_PLANE, nloc + l15, l4);                \
    bf16x8_t b1H = ld_frag(lds + 0 * XS_PLANE, nloc + 16 + l15, l4);           \
    bf16x8_t b0M = ld_frag(lds + 1 * XS_PLANE, nloc + l15, l4);                \
    bf16x8_t b1M = ld_frag(lds + 1 * XS_PLANE, nloc + 16 + l15, l4);           \
    bf16x8_t b0L = ld_frag(lds + 2 * XS_PLANE, nloc + l15, l4);                \
    bf16x8_t b1L = ld_frag(lds + 2 * XS_PLANE, nloc + 16 + l15, l4);           \
    acc00 = MFMA(a0H, b0H, acc00); acc01 = MFMA(a0H, b1H, acc01);              \
    acc10 = MFMA(a1H, b0H, acc10); acc11 = MFMA(a1H, b1H, acc11);              \
    acc00 = MFMA(a0H, b0M, acc00); acc01 = MFMA(a0H, b1M, acc01);              \
    acc10 = MFMA(a1H, b0M, acc10); acc11 = MFMA(a1H, b1M, acc11);              \
    acc00 = MFMA(a0M, b0H, acc00); acc01 = MFMA(a0M, b1H, acc01);              \
    acc10 = MFMA(a1M, b0H, acc10); acc11 = MFMA(a1M, b1H, acc11);              \
    acc00 = MFMA(a0M, b0M, acc00); acc01 = MFMA(a0M, b1M, acc01);              \
    acc10 = MFMA(a1M, b0M, acc10); acc11 = MFMA(a1M, b1M, acc11);              \
    acc00 = MFMA(a0H, b0L, acc00); acc01 = MFMA(a0H, b1L, acc01);              \
    acc10 = MFMA(a1H, b0L, acc10); acc11 = MFMA(a1H, b1L, acc11);              \
    acc00 = MFMA(a0L, b0H, acc00); acc01 = MFMA(a0L, b1H, acc01);              \
    acc10 = MFMA(a1L, b0H, acc10); acc11 = MFMA(a1L, b1H, acc11);              \
  }

// ---------------------------------------------------------------------------
// Kernel 1 (MFMA bf16x3; seed A-frags from L2): scores[b*Q+q][n] =
// dot(x[b,n,:], seed[q,:]). Grid 1024 blocks x 256 threads; block =
// (b=bid>>6, nb=bid&63), 128 n-rows, all 32 q; 24 chunks of 32 h; x
// reg-prefetch double buffer; 4 blocks/CU (4 barrier domains).
// ---------------------------------------------------------------------------
__global__ __launch_bounds__(256, 4) void k_scores(const float* __restrict__ x,
                                                   const uint4* __restrict__ sfrag,
                                                   float* __restrict__ scores) {
  __shared__ __align__(16) char lds[LDS_BYTES];

  const int tid = threadIdx.x;
  const int bid = blockIdx.x;
  const int b = bid >> 6;
  const int nb = bid & 63;
  const size_t xbase = ((size_t)b * N + (size_t)nb * 128) * H;

  const int lane = tid & 63;
  const int wave = tid >> 6;           // 0..3
  const int l15 = lane & 15;
  const int l4 = lane >> 4;
  const int nloc = wave * 32;

  // x staging: thread loads rows sn + r*32 at float offset sh (4 floats)
  const int sn = tid >> 3;             // 0..31
  const int sh = (tid & 7) << 2;       // 0,4,...,28

  f32x4_t acc00 = {0.f, 0.f, 0.f, 0.f};
  f32x4_t acc01 = {0.f, 0.f, 0.f, 0.f};
  f32x4_t acc10 = {0.f, 0.f, 0.f, 0.f};
  f32x4_t acc11 = {0.f, 0.f, 0.f, 0.f};

  float4 pxA[4], pxB[4];
  uint4 fA0, fA1, fA2, fA3, fA4, fA5;
  uint4 fB0, fB1, fB2, fB3, fB4, fB5;

  // prologue: chunk 0 -> A regs
  {
    const float* xp = x + xbase + sh;
#pragma unroll
    for (int r = 0; r < 4; ++r)
      pxA[r] = *reinterpret_cast<const float4*>(xp + (size_t)(sn + r * 32) * H);
  }

#pragma unroll 1
  for (int c = 0; c < 24; c += 2) {
    // prefetch x chunk c+1 -> B regs (issue before consuming A)
    {
      const float* xp = x + xbase + (c + 1) * 32 + sh;
#pragma unroll
      for (int r = 0; r < 4; ++r)
        pxB[r] = *reinterpret_cast<const float4*>(xp + (size_t)(sn + r * 32) * H);
    }
    STAGE_CHUNK(pxA);
    LOAD_AFRAGS(c, fA);
    __syncthreads();
    MFMA_CHUNK(fA);
    __syncthreads();

    // prefetch x chunk c+2 -> A regs
    if (c + 2 < 24) {
      const float* xp = x + xbase + (c + 2) * 32 + sh;
#pragma unroll
      for (int r = 0; r < 4; ++r)
        pxA[r] = *reinterpret_cast<const float4*>(xp + (size_t)(sn + r * 32) * H);
    }
    STAGE_CHUNK(pxB);
    LOAD_AFRAGS(c + 1, fB);
    __syncthreads();
    MFMA_CHUNK(fB);
    __syncthreads();
  }

  // epilogue: C[q][n]: q = qt*16 + l4*4 + r, n = nb*128 + nloc + nt*16 + l15
  float* srow = scores + (((size_t)(b * Q)) << 13) + nb * 128 + nloc;
#pragma unroll
  for (int r = 0; r < 4; ++r) {
    srow[((size_t)(l4 * 4 + r) << 13) + l15] = acc00[r];
    srow[((size_t)(l4 * 4 + r) << 13) + 16 + l15] = acc01[r];
    srow[((size_t)(16 + l4 * 4 + r) << 13) + l15] = acc10[r];
    srow[((size_t)(16 + l4 * 4 + r) << 13) + 16 + l15] = acc11[r];
  }
}

// ---------------------------------------------------------------------------
// Kernel 2 (unchanged): per (b,q) row: top-128 -> softmax -> gather V.
// Grid 512 blocks x 512 threads.
// ---------------------------------------------------------------------------
__global__ __launch_bounds__(512) void k_topk(const float* __restrict__ scores,
                                              const float* __restrict__ x,
                                              float* __restrict__ out) {
  const int bq = blockIdx.x;
  const int b = bq >> 5;
  const int tid = threadIdx.x;
  const float* srow = scores + ((size_t)bq << 13);

  // Load 16 scores per thread; build monotonic uint keys.
  float f[16];
  uint32_t u[16];
  const float4* s4 = reinterpret_cast<const float4*>(srow);
#pragma unroll
  for (int i = 0; i < 4; ++i) {
    float4 v = s4[i * 512 + tid];
    f[i * 4 + 0] = v.x; f[i * 4 + 1] = v.y;
    f[i * 4 + 2] = v.z; f[i * 4 + 3] = v.w;
  }
#pragma unroll
  for (int e = 0; e < 16; ++e) {
    uint32_t bits = __float_as_uint(f[e]);
    u[e] = (bits & 0x80000000u) ? ~bits : (bits | 0x80000000u);
  }

  // Binary search smallest T with count(u > T) < K.
  __shared__ int s_red[8];
  uint32_t lo = 0u, hi = 0xFFFFFFFFu;
  while (lo < hi) {
    uint32_t mid = lo + ((hi - lo) >> 1);
    int cnt = 0;
#pragma unroll
    for (int e = 0; e < 16; ++e) cnt += (u[e] > mid) ? 1 : 0;
#pragma unroll
    for (int m = 1; m < 64; m <<= 1) cnt += __shfl_xor(cnt, m);
    if ((tid & 63) == 0) s_red[tid >> 6] = cnt;
    __syncthreads();
    cnt = 0;
#pragma unroll
    for (int w = 0; w < 8; ++w) cnt += s_red[w];
    if (cnt >= K) lo = mid + 1; else hi = mid;
    __syncthreads();
  }
  const uint32_t T = lo;

  // Collect strictly-greater, then lowest-index ties == T.
  __shared__ int s_cnt, s_eqn;
  __shared__ int s_idx[K];
  __shared__ float s_w[K];
  __shared__ int s_eq[256];
  __shared__ float s_m, s_sum;
  if (tid == 0) { s_cnt = 0; s_eqn = 0; }
  __syncthreads();
#pragma unroll
  for (int e = 0; e < 16; ++e) {
    int n = (((e >> 2) * 512 + tid) << 2) + (e & 3);
    if (u[e] > T) {
      int p = atomicAdd(&s_cnt, 1);
      s_idx[p] = n;
      s_w[p] = f[e];
    } else if (u[e] == T) {
      int p = atomicAdd(&s_eqn, 1);
      if (p < 256) s_eq[p] = n;
    }
  }
  __syncthreads();
  const int c1 = s_cnt;
  const int need = K - c1;
  if (tid == 0 && need > 0) {
    uint32_t tb = (T & 0x80000000u) ? (T ^ 0x80000000u) : ~T;
    float tf = __uint_as_float(tb);
    int m = s_eqn; if (m > 256) m = 256;
    for (int a = 0; a < need; ++a) {       // selection-sort lowest indices
      int best = s_eq[a], bi = a;
      for (int z = a + 1; z < m; ++z)
        if (s_eq[z] < best) { best = s_eq[z]; bi = z; }
      s_eq[bi] = s_eq[a]; s_eq[a] = best;
      s_idx[c1 + a] = best;
      s_w[c1 + a] = tf;
    }
  }
  __syncthreads();

  // Softmax over the 128 selected values (store un-normalized exp in s_w).
  if (tid < 64) {
    float v = fmaxf(s_w[tid], s_w[tid + 64]);
#pragma unroll
    for (int m = 1; m < 64; m <<= 1) v = fmaxf(v, __shfl_xor(v, m));
    if (tid == 0) s_m = v;
  }
  __syncthreads();
  const float mx = s_m * SCALE;
  if (tid < K) s_w[tid] = __expf(s_w[tid] * SCALE - mx);
  __syncthreads();
  if (tid < 64) {
    float v = s_w[tid] + s_w[tid + 64];
#pragma unroll
    for (int m = 1; m < 64; m <<= 1) v += __shfl_xor(v, m);
    if (tid == 0) s_sum = v;
  }
  __syncthreads();

  // Gather + weighted sum: 2 k-slices x 192 threads x float4 (768 floats).
  __shared__ __align__(16) float s_part[H];   // 3 KiB
  {
    const int t = tid & 255;        // lane within slice
    const int ks = tid >> 8;        // k-slice: 0 or 1
    float4 acc = make_float4(0.f, 0.f, 0.f, 0.f);
    if (t < 192) {
      const float4* xb =
          reinterpret_cast<const float4*>(x + (((size_t)b) << 13) * H);
      const int k0 = ks << 6;
#pragma unroll 4
      for (int k = k0; k < k0 + 64; ++k) {
        const float w = s_w[k];
        const float4 v = xb[(size_t)s_idx[k] * (H / 4) + t];
        acc.x = fmaf(w, v.x, acc.x);
        acc.y = fmaf(w, v.y, acc.y);
        acc.z = fmaf(w, v.z, acc.z);
        acc.w = fmaf(w, v.w, acc.w);
      }
    }
    if (ks == 0 && t < 192)
      reinterpret_cast<float4*>(s_part)[t] = acc;
    __syncthreads();
    if (ks == 1 && t < 192) {
      const float4 p = reinterpret_cast<const float4*>(s_part)[t];
      const float inv = 1.f / s_sum;
      float4 o;
      o.x = (acc.x + p.x) * inv;
      o.y = (acc.y + p.y) * inv;
      o.z = (acc.z + p.z) * inv;
      o.w = (acc.w + p.w) * inv;
      reinterpret_cast<float4*>(out)[(size_t)bq * (H / 4) + t] = o;
    }
  }
}

extern "C" void kernel_launch(void* const* d_in, const int* in_sizes, int n_in,
                              void* d_out, int out_size, void* d_ws, size_t ws_size,
                              hipStream_t stream) {
  const float* x = (const float*)d_in[0];     // [B, N, H] f32
  const float* seed = (const float*)d_in[1];  // [1, Q, H] f32
  float* out = (float*)d_out;                 // [B, Q, H] f32
  float* scores = (float*)d_ws;               // [B*Q, N] f32 = 16 MiB scratch
  // seed fragments (144 KB) at the start of d_out; k_topk fully overwrites
  // d_out afterwards (validated round 7).
  uint4* sfrag = (uint4*)d_out;

  k_seedsplit<<<24, 64, 0, stream>>>(seed, sfrag);
  k_scores<<<1024, 256, 0, stream>>>(x, sfrag, scores);
  k_topk<<<512, 512, 0, stream>>>(scores, x, out);
}

// Round 13
// 118.692 us; speedup vs baseline: 1.1146x; 1.1146x over previous
//
#include <hip/hip_runtime.h>
#include <hip/hip_bf16.h>

// Problem constants (from reference)
constexpr int B = 16;
constexpr int N = 8192;
constexpr int H = 768;
constexpr int Q = 32;      // K_SEEDS
constexpr int K = 128;     // TOPK
#define SCALE 0.28867513459481287f   // 12^-0.5

typedef __attribute__((ext_vector_type(8))) short bf16x8_t;
typedef __attribute__((ext_vector_type(4))) float f32x4_t;

// LDS layout: xs[3 split][128 n][32 h] bf16 (row stride 64 B) + ss[3][32 q][32 h]
#define XS_OFF 0
#define XS_SPLIT 8192      // 128 rows * 64 B
#define SS_OFF 24576
#define SS_SPLIT 2048      // 32 rows * 64 B
#define LDS_BYTES 30720

__device__ __forceinline__ float bf16_to_f32(ushort h) {
  return __uint_as_float(((uint32_t)h) << 16);
}
// hardware v_cvt bf16 cast (RNE on gfx950)
__device__ __forceinline__ ushort cvt_bf16(float f) {
  __hip_bfloat16 h = __float2bfloat16(f);
  return __builtin_bit_cast(unsigned short, h);
}
// f32 -> bf16 hi/mid/lo via HW cvt; residuals Sterbenz-exact.
// 3-split/6-pass REQUIRED: round 9 measured that dropping the 2^-18 term
// families (mm,hl,lh) costs ~0.01 absmax each vs the 0.0108 threshold.
__device__ __forceinline__ void split3(float f, ushort& h, ushort& m, ushort& l) {
  h = cvt_bf16(f);
  float f1 = f - bf16_to_f32(h);
  m = cvt_bf16(f1);
  float f2 = f1 - bf16_to_f32(m);
  l = cvt_bf16(f2);
}

// swizzled frag read: 16 B at (row, 16-B sub-block l4), sub-block XOR'd by row
__device__ __forceinline__ bf16x8_t ld_frag(const char* p, int row, int l4) {
  int sb = l4 ^ ((row >> 1) & 3);
  return *reinterpret_cast<const bf16x8_t*>(p + row * 64 + (sb << 4));
}

#define MFMA(a, b, c) __builtin_amdgcn_mfma_f32_16x16x32_bf16(a, b, c, 0, 0, 0)

// Stage one 32-h chunk: split px (4 rows x 4 h) + ps (4 seed el) -> LDS
#define STAGE_CHUNK(PX, PS)                                                    \
  {                                                                            \
    _Pragma("unroll") for (int r = 0; r < 4; ++r) {                            \
      const int row = sn + r * 32;                                             \
      const int byt = sh * 2;                                                  \
      const int sb = (byt >> 4) ^ ((row >> 1) & 3);                            \
      char* dst = lds + XS_OFF + row * 64 + (sb << 4) + (byt & 15);            \
      ushort4 uh, um, ul;                                                      \
      split3(PX[r].x, uh.x, um.x, ul.x);                                       \
      split3(PX[r].y, uh.y, um.y, ul.y);                                       \
      split3(PX[r].z, uh.z, um.z, ul.z);                                       \
      split3(PX[r].w, uh.w, um.w, ul.w);                                       \
      *reinterpret_cast<ushort4*>(dst + 0 * XS_SPLIT) = uh;                    \
      *reinterpret_cast<ushort4*>(dst + 1 * XS_SPLIT) = um;                    \
      *reinterpret_cast<ushort4*>(dst + 2 * XS_SPLIT) = ul;                    \
    }                                                                          \
    {                                                                          \
      const int byt = sh * 2;                                                  \
      const int sb = (byt >> 4) ^ ((sq >> 1) & 3);                             \
      char* dst = lds + SS_OFF + sq * 64 + (sb << 4) + (byt & 15);             \
      ushort4 uh, um, ul;                                                      \
      split3(PS.x, uh.x, um.x, ul.x);                                          \
      split3(PS.y, uh.y, um.y, ul.y);                                          \
      split3(PS.z, uh.z, um.z, ul.z);                                          \
      split3(PS.w, uh.w, um.w, ul.w);                                          \
      *reinterpret_cast<ushort4*>(dst + 0 * SS_SPLIT) = uh;                    \
      *reinterpret_cast<ushort4*>(dst + 1 * SS_SPLIT) = um;                    \
      *reinterpret_cast<ushort4*>(dst + 2 * SS_SPLIT) = ul;                    \
    }                                                                          \
  }

// One chunk of MFMA: 12 frag reads + 24 mfma (6 passes x 4 C-tiles)
#define MFMA_CHUNK()                                                           \
  {                                                                            \
    const char* ssb = lds + SS_OFF;                                            \
    const char* xsb = lds + XS_OFF;                                            \
    bf16x8_t a0H = ld_frag(ssb + 0 * SS_SPLIT, l15, l4);                       \
    bf16x8_t a1H = ld_frag(ssb + 0 * SS_SPLIT, 16 + l15, l4);                  \
    bf16x8_t b0H = ld_frag(xsb + 0 * XS_SPLIT, nloc + l15, l4);                \
    bf16x8_t b1H = ld_frag(xsb + 0 * XS_SPLIT, nloc + 16 + l15, l4);           \
    bf16x8_t a0M = ld_frag(ssb + 1 * SS_SPLIT, l15, l4);                       \
    bf16x8_t a1M = ld_frag(ssb + 1 * SS_SPLIT, 16 + l15, l4);                  \
    bf16x8_t b0M = ld_frag(xsb + 1 * XS_SPLIT, nloc + l15, l4);                \
    bf16x8_t b1M = ld_frag(xsb + 1 * XS_SPLIT, nloc + 16 + l15, l4);           \
    bf16x8_t a0L = ld_frag(ssb + 2 * SS_SPLIT, l15, l4);                       \
    bf16x8_t a1L = ld_frag(ssb + 2 * SS_SPLIT, 16 + l15, l4);                  \
    bf16x8_t b0L = ld_frag(xsb + 2 * XS_SPLIT, nloc + l15, l4);                \
    bf16x8_t b1L = ld_frag(xsb + 2 * XS_SPLIT, nloc + 16 + l15, l4);           \
    acc00 = MFMA(a0H, b0H, acc00); acc01 = MFMA(a0H, b1H, acc01);              \
    acc10 = MFMA(a1H, b0H, acc10); acc11 = MFMA(a1H, b1H, acc11);              \
    acc00 = MFMA(a0H, b0M, acc00); acc01 = MFMA(a0H, b1M, acc01);              \
    acc10 = MFMA(a1H, b0M, acc10); acc11 = MFMA(a1H, b1M, acc11);              \
    acc00 = MFMA(a0M, b0H, acc00); acc01 = MFMA(a0M, b1H, acc01);              \
    acc10 = MFMA(a1M, b0H, acc10); acc11 = MFMA(a1M, b1H, acc11);              \
    acc00 = MFMA(a0M, b0M, acc00); acc01 = MFMA(a0M, b1M, acc01);              \
    acc10 = MFMA(a1M, b0M, acc10); acc11 = MFMA(a1M, b1M, acc11);              \
    acc00 = MFMA(a0H, b0L, acc00); acc01 = MFMA(a0H, b1L, acc01);              \
    acc10 = MFMA(a1H, b0L, acc10); acc11 = MFMA(a1H, b1L, acc11);              \
    acc00 = MFMA(a0L, b0H, acc00); acc01 = MFMA(a0L, b1H, acc01);              \
    acc10 = MFMA(a1L, b0H, acc10); acc11 = MFMA(a1L, b1H, acc11);              \
  }

// ---------------------------------------------------------------------------
// Kernel 1 (round-10 known-best): scores[b*Q+q][n] = dot(x[b,n,:], seed[q,:]).
// Grid 1024 blocks x 256 threads; block = (b = bid>>6, nb = bid&63), 128
// n-rows, all 32 q. 4 waves/block; 4 blocks/CU = 4 barrier domains.
// ---------------------------------------------------------------------------
__global__ __launch_bounds__(256, 4) void k_scores(const float* __restrict__ x,
                                                   const float* __restrict__ seed,
                                                   float* __restrict__ scores) {
  __shared__ __align__(16) char lds[LDS_BYTES];

  const int tid = threadIdx.x;
  const int bid = blockIdx.x;
  const int b = bid >> 6;
  const int nb = bid & 63;
  const size_t xbase = ((size_t)b * N + (size_t)nb * 128) * H;

  const int lane = tid & 63;
  const int wave = tid >> 6;           // 0..3
  const int l15 = lane & 15;
  const int l4 = lane >> 4;
  const int nloc = wave * 32;

  // staging indices: x: thread loads rows sn + r*32 at float offset sh (4 floats)
  const int sn = tid >> 3;           // 0..31
  const int sh = (tid & 7) << 2;     // 0,4,...,28
  // seed: thread loads 4 floats at (q = sq, h = sh)
  const int sq = tid >> 3;           // 0..31

  f32x4_t acc00 = {0.f, 0.f, 0.f, 0.f};
  f32x4_t acc01 = {0.f, 0.f, 0.f, 0.f};
  f32x4_t acc10 = {0.f, 0.f, 0.f, 0.f};
  f32x4_t acc11 = {0.f, 0.f, 0.f, 0.f};

  float4 pxA[4], pxB[4];
  float4 psA, psB;

  // prologue: chunk 0 -> A regs
  {
    const float* xp = x + xbase + sh;
#pragma unroll
    for (int r = 0; r < 4; ++r)
      pxA[r] = *reinterpret_cast<const float4*>(xp + (size_t)(sn + r * 32) * H);
    psA = *reinterpret_cast<const float4*>(seed + (size_t)sq * H + sh);
  }

#pragma unroll 1
  for (int c = 0; c < 24; c += 2) {
    // prefetch chunk c+1 -> B regs (issue before consuming A)
    {
      const float* xp = x + xbase + (c + 1) * 32 + sh;
#pragma unroll
      for (int r = 0; r < 4; ++r)
        pxB[r] = *reinterpret_cast<const float4*>(xp + (size_t)(sn + r * 32) * H);
      psB = *reinterpret_cast<const float4*>(seed + (size_t)sq * H + (c + 1) * 32 + sh);
    }
    STAGE_CHUNK(pxA, psA);
    __syncthreads();
    MFMA_CHUNK();
    __syncthreads();

    // prefetch chunk c+2 -> A regs
    if (c + 2 < 24) {
      const float* xp = x + xbase + (c + 2) * 32 + sh;
#pragma unroll
      for (int r = 0; r < 4; ++r)
        pxA[r] = *reinterpret_cast<const float4*>(xp + (size_t)(sn + r * 32) * H);
      psA = *reinterpret_cast<const float4*>(seed + (size_t)sq * H + (c + 2) * 32 + sh);
    }
    STAGE_CHUNK(pxB, psB);
    __syncthreads();
    MFMA_CHUNK();
    __syncthreads();
  }

  // epilogue: C[q][n]: q = qt*16 + l4*4 + r, n = nb*128 + nloc + nt*16 + l15
  float* srow = scores + (((size_t)(b * Q)) << 13) + nb * 128 + nloc;
#pragma unroll
  for (int r = 0; r < 4; ++r) {
    srow[((size_t)(l4 * 4 + r) << 13) + l15] = acc00[r];
    srow[((size_t)(l4 * 4 + r) << 13) + 16 + l15] = acc01[r];
    srow[((size_t)(16 + l4 * 4 + r) << 13) + l15] = acc10[r];
    srow[((size_t)(16 + l4 * 4 + r) << 13) + 16 + l15] = acc11[r];
  }
}

// ---------------------------------------------------------------------------
// Kernel 2: per (b,q) row: top-128 -> softmax -> gather V.
// Grid 512 blocks x 512 threads. XCD-grouping remap: b = bid&15, q = bid>>4
// puts all 32 q-blocks of one batch on XCD b%8 (bid%8 is constant for fixed
// b) so their ~22% gather-row overlap becomes L2-servable.
// ---------------------------------------------------------------------------
__global__ __launch_bounds__(512) void k_topk(const float* __restrict__ scores,
                                              const float* __restrict__ x,
                                              float* __restrict__ out) {
  const int b = blockIdx.x & 15;
  const int q = blockIdx.x >> 4;
  const int bq = (b << 5) | q;
  const int tid = threadIdx.x;
  const float* srow = scores + ((size_t)bq << 13);

  // Load 16 scores per thread; build monotonic uint keys.
  float f[16];
  uint32_t u[16];
  const float4* s4 = reinterpret_cast<const float4*>(srow);
#pragma unroll
  for (int i = 0; i < 4; ++i) {
    float4 v = s4[i * 512 + tid];
    f[i * 4 + 0] = v.x; f[i * 4 + 1] = v.y;
    f[i * 4 + 2] = v.z; f[i * 4 + 3] = v.w;
  }
#pragma unroll
  for (int e = 0; e < 16; ++e) {
    uint32_t bits = __float_as_uint(f[e]);
    u[e] = (bits & 0x80000000u) ? ~bits : (bits | 0x80000000u);
  }

  // Binary search smallest T with count(u > T) < K.
  __shared__ int s_red[8];
  uint32_t lo = 0u, hi = 0xFFFFFFFFu;
  while (lo < hi) {
    uint32_t mid = lo + ((hi - lo) >> 1);
    int cnt = 0;
#pragma unroll
    for (int e = 0; e < 16; ++e) cnt += (u[e] > mid) ? 1 : 0;
#pragma unroll
    for (int m = 1; m < 64; m <<= 1) cnt += __shfl_xor(cnt, m);
    if ((tid & 63) == 0) s_red[tid >> 6] = cnt;
    __syncthreads();
    cnt = 0;
#pragma unroll
    for (int w = 0; w < 8; ++w) cnt += s_red[w];
    if (cnt >= K) lo = mid + 1; else hi = mid;
    __syncthreads();
  }
  const uint32_t T = lo;

  // Collect strictly-greater, then lowest-index ties == T.
  __shared__ int s_cnt, s_eqn;
  __shared__ int s_idx[K];
  __shared__ float s_w[K];
  __shared__ int s_eq[256];
  __shared__ float s_m, s_sum;
  if (tid == 0) { s_cnt = 0; s_eqn = 0; }
  __syncthreads();
#pragma unroll
  for (int e = 0; e < 16; ++e) {
    int n = (((e >> 2) * 512 + tid) << 2) + (e & 3);
    if (u[e] > T) {
      int p = atomicAdd(&s_cnt, 1);
      s_idx[p] = n;
      s_w[p] = f[e];
    } else if (u[e] == T) {
      int p = atomicAdd(&s_eqn, 1);
      if (p < 256) s_eq[p] = n;
    }
  }
  __syncthreads();
  const int c1 = s_cnt;
  const int need = K - c1;
  if (tid == 0 && need > 0) {
    uint32_t tb = (T & 0x80000000u) ? (T ^ 0x80000000u) : ~T;
    float tf = __uint_as_float(tb);
    int m = s_eqn; if (m > 256) m = 256;
    for (int a = 0; a < need; ++a) {       // selection-sort lowest indices
      int best = s_eq[a], bi = a;
      for (int z = a + 1; z < m; ++z)
        if (s_eq[z] < best) { best = s_eq[z]; bi = z; }
      s_eq[bi] = s_eq[a]; s_eq[a] = best;
      s_idx[c1 + a] = best;
      s_w[c1 + a] = tf;
    }
  }
  __syncthreads();

  // Softmax over the 128 selected values (store un-normalized exp in s_w).
  if (tid < 64) {
    float v = fmaxf(s_w[tid], s_w[tid + 64]);
#pragma unroll
    for (int m = 1; m < 64; m <<= 1) v = fmaxf(v, __shfl_xor(v, m));
    if (tid == 0) s_m = v;
  }
  __syncthreads();
  const float mx = s_m * SCALE;
  if (tid < K) s_w[tid] = __expf(s_w[tid] * SCALE - mx);
  __syncthreads();
  if (tid < 64) {
    float v = s_w[tid] + s_w[tid + 64];
#pragma unroll
    for (int m = 1; m < 64; m <<= 1) v += __shfl_xor(v, m);
    if (tid == 0) s_sum = v;
  }
  __syncthreads();

  // Gather + weighted sum: 2 k-slices x 192 threads x float4 (768 floats).
  __shared__ __align__(16) float s_part[H];   // 3 KiB
  {
    const int t = tid & 255;        // lane within slice
    const int ks = tid >> 8;        // k-slice: 0 or 1
    float4 acc = make_float4(0.f, 0.f, 0.f, 0.f);
    if (t < 192) {
      const float4* xb =
          reinterpret_cast<const float4*>(x + (((size_t)b) << 13) * H);
      const int k0 = ks << 6;
#pragma unroll 4
      for (int k = k0; k < k0 + 64; ++k) {
        const float w = s_w[k];
        const float4 v = xb[(size_t)s_idx[k] * (H / 4) + t];
        acc.x = fmaf(w, v.x, acc.x);
        acc.y = fmaf(w, v.y, acc.y);
        acc.z = fmaf(w, v.z, acc.z);
        acc.w = fmaf(w, v.w, acc.w);
      }
    }
    if (ks == 0 && t < 192)
      reinterpret_cast<float4*>(s_part)[t] = acc;
    __syncthreads();
    if (ks == 1 && t < 192) {
      const float4 p = reinterpret_cast<const float4*>(s_part)[t];
      const float inv = 1.f / s_sum;
      float4 o;
      o.x = (acc.x + p.x) * inv;
      o.y = (acc.y + p.y) * inv;
      o.z = (acc.z + p.z) * inv;
      o.w = (acc.w + p.w) * inv;
      reinterpret_cast<float4*>(out)[(size_t)bq * (H / 4) + t] = o;
    }
  }
}

extern "C" void kernel_launch(void* const* d_in, const int* in_sizes, int n_in,
                              void* d_out, int out_size, void* d_ws, size_t ws_size,
                              hipStream_t stream) {
  const float* x = (const float*)d_in[0];     // [B, N, H] f32
  const float* seed = (const float*)d_in[1];  // [1, Q, H] f32
  float* out = (float*)d_out;                 // [B, Q, H] f32
  float* scores = (float*)d_ws;               // [B*Q, N] f32 = 16 MiB scratch

  k_scores<<<1024, 256, 0, stream>>>(x, seed, scores);
  k_topk<<<512, 512, 0, stream>>>(scores, x, out);
}